// Round 1
// baseline (845.828 us; speedup 1.0000x reference)
//
#include <hip/hip_runtime.h>
#include <math.h>

#define B_ 16
#define M_ 1024
#define N_ 1024
#define D_ 512
#define MP1 1025
#define NP1 1025
#define NUM_SINK 8
// log(1/2048), log(1/2)
#define LOG_NORM (-7.6246189861593985f)
#define LOG_HALF (-0.6931471805599453f)

// ---------------- norms: one wave per feature row ----------------
__global__ __launch_bounds__(256) void norms_kernel(
    const float* __restrict__ tf, const float* __restrict__ df,
    float* __restrict__ inv1, float* __restrict__ inv2)
{
    int w = (blockIdx.x * 256 + threadIdx.x) >> 6;
    int lane = threadIdx.x & 63;
    if (w >= B_ * 2048) return;
    int b = w >> 11;
    int rr = w & 2047;
    const float* src;
    float* dst;
    if (rr < M_) { src = tf + ((size_t)b * M_ + rr) * D_;        dst = inv1 + b * M_ + rr; }
    else         { src = df + ((size_t)b * N_ + (rr - M_)) * D_; dst = inv2 + b * N_ + (rr - M_); }
    float4 x = *(const float4*)(src + lane * 4);
    float4 y = *(const float4*)(src + 256 + lane * 4);
    float ss = x.x*x.x + x.y*x.y + x.z*x.z + x.w*x.w
             + y.x*y.x + y.y*y.y + y.z*y.z + y.w*y.w;
    #pragma unroll
    for (int o = 32; o; o >>= 1) ss += __shfl_xor(ss, o);
    if (lane == 0) *dst = 1.0f / sqrtf(ss);
}

// ---------------- GEMM + epilogue: write s = (corr*mask - 1)/lambda ----------------
// 128x128 tile, BK=16, 256 threads, 8x8 per thread (fp32 VALU)
__global__ __launch_bounds__(256) void gemm_s_kernel(
    const float* __restrict__ A, const float* __restrict__ Bm,
    const float* __restrict__ tl, const float* __restrict__ dl,
    const float* __restrict__ inv1, const float* __restrict__ inv2,
    const float* __restrict__ eps_p, float* __restrict__ S)
{
    __shared__ float As[16][128];
    __shared__ float Bs[16][128];
    int b  = blockIdx.z;
    int i0 = blockIdx.y * 128;
    int j0 = blockIdx.x * 128;
    const float* Ab = A  + (size_t)b * M_ * D_;
    const float* Bb = Bm + (size_t)b * N_ * D_;
    int tid = threadIdx.x;
    int kk = tid & 15;
    int r0 = tid >> 4;
    int tx = tid & 15, ty = tid >> 4;

    float c[8][8] = {};
    for (int k0 = 0; k0 < D_; k0 += 16) {
        #pragma unroll
        for (int rr = 0; rr < 8; ++rr) {
            int r = r0 + rr * 16;
            As[kk][r] = Ab[(size_t)(i0 + r) * D_ + k0 + kk];
            Bs[kk][r] = Bb[(size_t)(j0 + r) * D_ + k0 + kk];
        }
        __syncthreads();
        #pragma unroll
        for (int k = 0; k < 16; ++k) {
            float4 a0 = *(const float4*)&As[k][ty * 8];
            float4 a1 = *(const float4*)&As[k][ty * 8 + 4];
            float4 b0 = *(const float4*)&Bs[k][tx * 8];
            float4 b1 = *(const float4*)&Bs[k][tx * 8 + 4];
            float av[8] = {a0.x, a0.y, a0.z, a0.w, a1.x, a1.y, a1.z, a1.w};
            float bv[8] = {b0.x, b0.y, b0.z, b0.w, b1.x, b1.y, b1.z, b1.w};
            #pragma unroll
            for (int ii = 0; ii < 8; ++ii)
                #pragma unroll
                for (int jj = 0; jj < 8; ++jj)
                    c[ii][jj] = fmaf(av[ii], bv[jj], c[ii][jj]);
        }
        __syncthreads();
    }

    float lam = expf(eps_p[0]) + 0.03f;
    float inv_lam = 1.0f / lam;
    int ibase = i0 + ty * 8;
    int jbase = j0 + tx * 8;

    float inva[8], tlx_[8], tly_[8];
    float invb[8], dlx_[8], dly_[8];
    #pragma unroll
    for (int ii = 0; ii < 8; ++ii) {
        int i = ibase + ii;
        inva[ii] = inv1[b * M_ + i];
        tlx_[ii] = tl[((size_t)b * M_ + i) * 2 + 0];
        tly_[ii] = tl[((size_t)b * M_ + i) * 2 + 1];
    }
    #pragma unroll
    for (int jj = 0; jj < 8; ++jj) {
        int j = jbase + jj;
        invb[jj] = inv2[b * N_ + j];
        dlx_[jj] = dl[((size_t)b * N_ + j) * 2 + 0];
        dly_[jj] = dl[((size_t)b * N_ + j) * 2 + 1];
    }
    #pragma unroll
    for (int ii = 0; ii < 8; ++ii) {
        size_t rowoff = ((size_t)b * MP1 + (ibase + ii)) * NP1;
        #pragma unroll
        for (int jj = 0; jj < 8; ++jj) {
            float cosv = c[ii][jj] * inva[ii] * invb[jj];
            float dx = tlx_[ii] - dlx_[jj];
            float dy = tly_[ii] - dly_[jj];
            float msk = (sqrtf(dx * dx + dy * dy) <= 0.3f) ? 1.0f : 0.0f;
            S[rowoff + (jbase + jj)] = (cosv * msk - 1.0f) * inv_lam;
        }
    }
}

// ---------------- fill dustbin row/col with (alpha-1)/lambda ----------------
__global__ __launch_bounds__(256) void fill_edges_kernel(
    float* __restrict__ S, const float* __restrict__ alpha_p, const float* __restrict__ eps_p)
{
    int t = blockIdx.x * 256 + threadIdx.x;
    if (t >= B_ * (NP1 + M_)) return;   // 1025 last-row cols + 1024 last-col rows
    int b = t / (NP1 + M_), r = t % (NP1 + M_);
    float lam = expf(eps_p[0]) + 0.03f;
    float s = (alpha_p[0] - 1.0f) / lam;
    if (r < NP1) S[((size_t)b * MP1 + M_) * NP1 + r] = s;           // last row (incl corner)
    else         S[((size_t)b * MP1 + (r - NP1)) * NP1 + N_] = s;   // last col
}

// ---------------- row pass: u_i = log_a_i - lse_j(s_ij + v_j), one wave/row ----------------
__global__ __launch_bounds__(256) void row_pass_kernel(
    const float* __restrict__ S, const float* __restrict__ v, float* __restrict__ u)
{
    int w = (blockIdx.x * 256 + threadIdx.x) >> 6;
    int lane = threadIdx.x & 63;
    if (w >= B_ * MP1) return;
    int b = w / MP1, i = w % MP1;
    const float* row = S + ((size_t)b * MP1 + i) * NP1;
    const float* vb = v + b * NP1;
    float t[17];
    float mx = -INFINITY;
    #pragma unroll
    for (int q = 0; q < 17; ++q) {
        int j = lane + q * 64;
        float val = -INFINITY;
        if (j < NP1) val = row[j] + vb[j];
        t[q] = val;
        mx = fmaxf(mx, val);
    }
    #pragma unroll
    for (int o = 32; o; o >>= 1) mx = fmaxf(mx, __shfl_xor(mx, o));
    float sm = 0.f;
    #pragma unroll
    for (int q = 0; q < 17; ++q) sm += expf(t[q] - mx);
    #pragma unroll
    for (int o = 32; o; o >>= 1) sm += __shfl_xor(sm, o);
    if (lane == 0) {
        float la = (i == M_) ? LOG_HALF : LOG_NORM;
        u[b * MP1 + i] = la - (mx + logf(sm));
    }
}

// ---------------- col pass stage 1: partial lse over 128-row chunks ----------------
__global__ __launch_bounds__(256) void col_pass1_kernel(
    const float* __restrict__ S, const float* __restrict__ u,
    float* __restrict__ pm, float* __restrict__ ps)
{
    int j = blockIdx.x * 256 + threadIdx.x;
    int b = blockIdx.z;
    int i0 = blockIdx.y * 128;
    int i1 = min(i0 + 128, MP1);
    if (j >= NP1) return;
    const float* p  = S + ((size_t)b * MP1 + i0) * NP1 + j;
    const float* ub = u + b * MP1;
    float m = -INFINITY, sm = 0.f;
    for (int i = i0; i < i1; ++i) {
        float val = *p + ub[i];
        float nm = fmaxf(m, val);
        sm = sm * expf(m - nm) + expf(val - nm);
        m = nm;
        p += NP1;
    }
    int idx = (blockIdx.y * B_ + b) * NP1 + j;
    pm[idx] = m;
    ps[idx] = sm;
}

// ---------------- col pass stage 2: combine 9 partials, write v ----------------
__global__ __launch_bounds__(256) void col_pass2_kernel(
    const float* __restrict__ pm, const float* __restrict__ ps, float* __restrict__ v)
{
    int j = blockIdx.x * 256 + threadIdx.x;
    int b = blockIdx.y;
    if (j >= NP1) return;
    float M = -INFINITY;
    #pragma unroll
    for (int c = 0; c < 9; ++c) M = fmaxf(M, pm[(c * B_ + b) * NP1 + j]);
    float Ssum = 0.f;
    #pragma unroll
    for (int c = 0; c < 9; ++c) Ssum += ps[(c * B_ + b) * NP1 + j] * expf(pm[(c * B_ + b) * NP1 + j] - M);
    float lb = (j == N_) ? LOG_HALF : LOG_NORM;
    v[b * NP1 + j] = lb - (M + logf(Ssum));
}

// ---------------- finalize: out = exp(s + u_i + v_j) * (m+n), in place ----------------
__global__ __launch_bounds__(256) void finalize_kernel(
    float* __restrict__ S, const float* __restrict__ u, const float* __restrict__ v)
{
    unsigned idx = blockIdx.x * 256u + threadIdx.x;
    const unsigned total = (unsigned)B_ * MP1 * NP1;
    if (idx >= total) return;
    unsigned b = idx / (MP1 * NP1);
    unsigned rem = idx % (MP1 * NP1);
    unsigned i = rem / NP1;
    unsigned j = rem % NP1;
    S[idx] = expf(S[idx] + u[b * MP1 + i] + v[b * NP1 + j]) * 2048.0f;
}

// ---------------- zero helper ----------------
__global__ __launch_bounds__(256) void zero_kernel(float* __restrict__ p, int n)
{
    int i = blockIdx.x * 256 + threadIdx.x;
    if (i < n) p[i] = 0.f;
}

extern "C" void kernel_launch(void* const* d_in, const int* in_sizes, int n_in,
                              void* d_out, int out_size, void* d_ws, size_t ws_size,
                              hipStream_t stream)
{
    const float* tf    = (const float*)d_in[0];
    const float* df    = (const float*)d_in[1];
    const float* tl    = (const float*)d_in[2];
    const float* dl    = (const float*)d_in[3];
    const float* alpha = (const float*)d_in[4];
    const float* eps   = (const float*)d_in[5];
    float* S  = (float*)d_out;
    float* ws = (float*)d_ws;

    float* inv1 = ws;                       // B*1024
    float* inv2 = inv1 + B_ * M_;           // B*1024
    float* u    = inv2 + B_ * N_;           // B*1025
    float* v    = u + B_ * MP1;             // B*1025
    float* pm   = v + B_ * NP1;             // 9*B*1025
    float* ps   = pm + 9 * B_ * NP1;        // 9*B*1025

    // v must be zero at the start of every call (ws is not re-poisoned)
    zero_kernel<<<(B_ * NP1 + 255) / 256, 256, 0, stream>>>(v, B_ * NP1);
    norms_kernel<<<(B_ * 2048) / 4, 256, 0, stream>>>(tf, df, inv1, inv2);
    gemm_s_kernel<<<dim3(8, 8, 16), 256, 0, stream>>>(tf, df, tl, dl, inv1, inv2, eps, S);
    fill_edges_kernel<<<(B_ * (NP1 + M_) + 255) / 256, 256, 0, stream>>>(S, alpha, eps);

    int rowblocks = (B_ * MP1 + 3) / 4;   // 4 waves (rows) per 256-thread block
    for (int it = 0; it < NUM_SINK; ++it) {
        row_pass_kernel<<<rowblocks, 256, 0, stream>>>(S, v, u);
        col_pass1_kernel<<<dim3(5, 9, 16), 256, 0, stream>>>(S, u, pm, ps);
        col_pass2_kernel<<<dim3(5, 16), 256, 0, stream>>>(pm, ps, v);
    }
    row_pass_kernel<<<rowblocks, 256, 0, stream>>>(S, v, u);

    unsigned total = (unsigned)B_ * MP1 * NP1;
    finalize_kernel<<<(total + 255) / 256, 256, 0, stream>>>(S, u, v);
}

// Round 2
// 613.367 us; speedup vs baseline: 1.3790x; 1.3790x over previous
//
#include <hip/hip_runtime.h>
#include <math.h>

#define B_ 16
#define M_ 1024
#define N_ 1024
#define D_ 512
#define MP1 1025
#define NP1 1025
#define NUM_SINK 8
#define BK 64
// log(1/2048), log(1/2)
#define LOG_NORM (-7.6246189861593985f)
#define LOG_HALF (-0.6931471805599453f)

typedef __attribute__((ext_vector_type(8))) short bf16x8;
typedef __attribute__((ext_vector_type(4))) float f32x4;

__device__ inline short f2bf(float x) {
    unsigned u = __builtin_bit_cast(unsigned, x);
    u = (u + 0x7FFFu + ((u >> 16) & 1u)) >> 16;
    return (short)u;
}

// ---------------- norms: one wave per feature row ----------------
__global__ __launch_bounds__(256) void norms_kernel(
    const float* __restrict__ tf, const float* __restrict__ df,
    float* __restrict__ inv1, float* __restrict__ inv2)
{
    int w = (blockIdx.x * 256 + threadIdx.x) >> 6;
    int lane = threadIdx.x & 63;
    if (w >= B_ * 2048) return;
    int b = w >> 11;
    int rr = w & 2047;
    const float* src;
    float* dst;
    if (rr < M_) { src = tf + ((size_t)b * M_ + rr) * D_;        dst = inv1 + b * M_ + rr; }
    else         { src = df + ((size_t)b * N_ + (rr - M_)) * D_; dst = inv2 + b * N_ + (rr - M_); }
    float4 x = *(const float4*)(src + lane * 4);
    float4 y = *(const float4*)(src + 256 + lane * 4);
    float ss = x.x*x.x + x.y*x.y + x.z*x.z + x.w*x.w
             + y.x*y.x + y.y*y.y + y.z*y.z + y.w*y.w;
    #pragma unroll
    for (int o = 32; o; o >>= 1) ss += __shfl_xor(ss, o);
    if (lane == 0) *dst = 1.0f / sqrtf(ss);
}

// ---------------- MFMA GEMM + epilogue: S = (cos*mask - 1)/lambda ----------------
// 128x128 tile, BK=64, 256 threads = 4 waves (2x2), 4x4 fragments of 16x16x32 bf16
__global__ __launch_bounds__(256) void gemm_s_kernel(
    const float* __restrict__ A, const float* __restrict__ Bm,
    const float* __restrict__ tl, const float* __restrict__ dl,
    const float* __restrict__ inv1, const float* __restrict__ inv2,
    const float* __restrict__ eps_p, float* __restrict__ S)
{
    __shared__ __align__(16) unsigned short As[128 * BK];   // 16 KB, row stride 128 B
    __shared__ __align__(16) unsigned short Bs[128 * BK];   // 16 KB

    int b  = blockIdx.z;
    int i0 = blockIdx.y * 128;
    int j0 = blockIdx.x * 128;
    const float* Ab = A  + (size_t)b * M_ * D_;
    const float* Bb = Bm + (size_t)b * N_ * D_;

    int tid  = threadIdx.x;
    int lane = tid & 63;
    int w    = tid >> 6;
    int wm   = w >> 1, wn = w & 1;

    // staging decomposition: 8 threads/row (16B of bf16 each), 32 row-groups
    int seg   = tid & 7;          // which 8-fp32 chunk along K
    int rbase = tid >> 3;         // 0..31

    f32x4 acc[4][4] = {};

    for (int k0 = 0; k0 < D_; k0 += BK) {
        #pragma unroll
        for (int rr = 0; rr < 4; ++rr) {
            int r = rbase + rr * 32;
            int colx = (seg * 16) ^ ((r & 7) << 4);   // swizzled byte offset in row
            {
                const float* pa = Ab + (size_t)(i0 + r) * D_ + k0 + seg * 8;
                float4 a0 = *(const float4*)pa;
                float4 a1 = *(const float4*)(pa + 4);
                bf16x8 hv;
                hv[0] = f2bf(a0.x); hv[1] = f2bf(a0.y); hv[2] = f2bf(a0.z); hv[3] = f2bf(a0.w);
                hv[4] = f2bf(a1.x); hv[5] = f2bf(a1.y); hv[6] = f2bf(a1.z); hv[7] = f2bf(a1.w);
                *(bf16x8*)((char*)As + r * 128 + colx) = hv;
            }
            {
                const float* pb = Bb + (size_t)(j0 + r) * D_ + k0 + seg * 8;
                float4 b0 = *(const float4*)pb;
                float4 b1 = *(const float4*)(pb + 4);
                bf16x8 hv;
                hv[0] = f2bf(b0.x); hv[1] = f2bf(b0.y); hv[2] = f2bf(b0.z); hv[3] = f2bf(b0.w);
                hv[4] = f2bf(b1.x); hv[5] = f2bf(b1.y); hv[6] = f2bf(b1.z); hv[7] = f2bf(b1.w);
                *(bf16x8*)((char*)Bs + r * 128 + colx) = hv;
            }
        }
        __syncthreads();

        #pragma unroll
        for (int ks = 0; ks < 2; ++ks) {
            int kb = ks * 64 + ((lane >> 4) << 4);   // byte offset along K
            bf16x8 af[4], bfr[4];
            #pragma unroll
            for (int m = 0; m < 4; ++m) {
                int ra = wm * 64 + m * 16 + (lane & 15);
                af[m] = *(const bf16x8*)((const char*)As + ra * 128 + (kb ^ ((ra & 7) << 4)));
                int rb = wn * 64 + m * 16 + (lane & 15);
                bfr[m] = *(const bf16x8*)((const char*)Bs + rb * 128 + (kb ^ ((rb & 7) << 4)));
            }
            #pragma unroll
            for (int m = 0; m < 4; ++m)
                #pragma unroll
                for (int n = 0; n < 4; ++n)
                    acc[m][n] = __builtin_amdgcn_mfma_f32_16x16x32_bf16(af[m], bfr[n], acc[m][n], 0, 0, 0);
        }
        __syncthreads();
    }

    // epilogue
    float lam = expf(eps_p[0]) + 0.03f;
    float inv_lam = 1.0f / lam;
    int crow0 = i0 + wm * 64;
    int ccol0 = j0 + wn * 64;
    int rlane = lane >> 4;     // 0..3
    int clane = lane & 15;

    float invb_[4], dlx_[4], dly_[4];
    #pragma unroll
    for (int n = 0; n < 4; ++n) {
        int j = ccol0 + n * 16 + clane;
        invb_[n] = inv2[b * N_ + j];
        dlx_[n]  = dl[((size_t)b * N_ + j) * 2 + 0];
        dly_[n]  = dl[((size_t)b * N_ + j) * 2 + 1];
    }
    #pragma unroll
    for (int m = 0; m < 4; ++m) {
        #pragma unroll
        for (int reg = 0; reg < 4; ++reg) {
            int i = crow0 + m * 16 + rlane * 4 + reg;
            float inva = inv1[b * M_ + i];
            float tlx  = tl[((size_t)b * M_ + i) * 2 + 0];
            float tly  = tl[((size_t)b * M_ + i) * 2 + 1];
            size_t rowoff = ((size_t)b * MP1 + i) * NP1;
            #pragma unroll
            for (int n = 0; n < 4; ++n) {
                float cosv = acc[m][n][reg] * inva * invb_[n];
                float dx = tlx - dlx_[n];
                float dy = tly - dly_[n];
                float msk = (sqrtf(dx * dx + dy * dy) <= 0.3f) ? 1.0f : 0.0f;
                S[rowoff + ccol0 + n * 16 + clane] = (cosv * msk - 1.0f) * inv_lam;
            }
        }
    }
}

// ---------------- fill dustbin row/col with (alpha-1)/lambda ----------------
__global__ __launch_bounds__(256) void fill_edges_kernel(
    float* __restrict__ S, const float* __restrict__ alpha_p, const float* __restrict__ eps_p)
{
    int t = blockIdx.x * 256 + threadIdx.x;
    if (t >= B_ * (NP1 + M_)) return;
    int b = t / (NP1 + M_), r = t % (NP1 + M_);
    float lam = expf(eps_p[0]) + 0.03f;
    float s = (alpha_p[0] - 1.0f) / lam;
    if (r < NP1) S[((size_t)b * MP1 + M_) * NP1 + r] = s;
    else         S[((size_t)b * MP1 + (r - NP1)) * NP1 + N_] = s;
}

// ---------------- row pass: u_i = log_a_i - lse_j(s_ij + v_j), one wave/row ----------------
__global__ __launch_bounds__(256) void row_pass_kernel(
    const float* __restrict__ S, const float* __restrict__ v, float* __restrict__ u)
{
    int w = (blockIdx.x * 256 + threadIdx.x) >> 6;
    int lane = threadIdx.x & 63;
    if (w >= B_ * MP1) return;
    int b = w / MP1, i = w % MP1;
    const float* row = S + ((size_t)b * MP1 + i) * NP1;
    const float* vb = v + b * NP1;
    float t[17];
    float mx = -INFINITY;
    #pragma unroll
    for (int q = 0; q < 17; ++q) {
        int j = lane + q * 64;
        float val = -INFINITY;
        if (j < NP1) val = row[j] + vb[j];
        t[q] = val;
        mx = fmaxf(mx, val);
    }
    #pragma unroll
    for (int o = 32; o; o >>= 1) mx = fmaxf(mx, __shfl_xor(mx, o));
    float sm = 0.f;
    #pragma unroll
    for (int q = 0; q < 17; ++q) sm += expf(t[q] - mx);
    #pragma unroll
    for (int o = 32; o; o >>= 1) sm += __shfl_xor(sm, o);
    if (lane == 0) {
        float la = (i == M_) ? LOG_HALF : LOG_NORM;
        u[b * MP1 + i] = la - (mx + logf(sm));
    }
}

// ---------------- col pass stage 1: partial lse over 128-row chunks ----------------
__global__ __launch_bounds__(256) void col_pass1_kernel(
    const float* __restrict__ S, const float* __restrict__ u,
    float* __restrict__ pm, float* __restrict__ ps)
{
    int j = blockIdx.x * 256 + threadIdx.x;
    int b = blockIdx.z;
    int i0 = blockIdx.y * 128;
    int i1 = min(i0 + 128, MP1);
    if (j >= NP1) return;
    const float* p  = S + ((size_t)b * MP1 + i0) * NP1 + j;
    const float* ub = u + b * MP1;
    float m = -INFINITY, sm = 0.f;
    for (int i = i0; i < i1; ++i) {
        float val = *p + ub[i];
        float nm = fmaxf(m, val);
        sm = sm * expf(m - nm) + expf(val - nm);
        m = nm;
        p += NP1;
    }
    int idx = (blockIdx.y * B_ + b) * NP1 + j;
    pm[idx] = m;
    ps[idx] = sm;
}

// ---------------- col pass stage 2: combine 9 partials, write v ----------------
__global__ __launch_bounds__(256) void col_pass2_kernel(
    const float* __restrict__ pm, const float* __restrict__ ps, float* __restrict__ v)
{
    int j = blockIdx.x * 256 + threadIdx.x;
    int b = blockIdx.y;
    if (j >= NP1) return;
    float M = -INFINITY;
    #pragma unroll
    for (int c = 0; c < 9; ++c) M = fmaxf(M, pm[(c * B_ + b) * NP1 + j]);
    float Ssum = 0.f;
    #pragma unroll
    for (int c = 0; c < 9; ++c) Ssum += ps[(c * B_ + b) * NP1 + j] * expf(pm[(c * B_ + b) * NP1 + j] - M);
    float lb = (j == N_) ? LOG_HALF : LOG_NORM;
    v[b * NP1 + j] = lb - (M + logf(Ssum));
}

// ---------------- fused final row pass + finalize: out = exp(t + la - lse)*2048 ----------------
__global__ __launch_bounds__(256) void row_final_kernel(
    float* __restrict__ S, const float* __restrict__ v)
{
    int w = (blockIdx.x * 256 + threadIdx.x) >> 6;
    int lane = threadIdx.x & 63;
    if (w >= B_ * MP1) return;
    int b = w / MP1, i = w % MP1;
    float* row = S + ((size_t)b * MP1 + i) * NP1;
    const float* vb = v + b * NP1;
    float t[17];
    float mx = -INFINITY;
    #pragma unroll
    for (int q = 0; q < 17; ++q) {
        int j = lane + q * 64;
        float val = -INFINITY;
        if (j < NP1) val = row[j] + vb[j];
        t[q] = val;
        mx = fmaxf(mx, val);
    }
    #pragma unroll
    for (int o = 32; o; o >>= 1) mx = fmaxf(mx, __shfl_xor(mx, o));
    float sm = 0.f;
    #pragma unroll
    for (int q = 0; q < 17; ++q) sm += expf(t[q] - mx);
    #pragma unroll
    for (int o = 32; o; o >>= 1) sm += __shfl_xor(sm, o);
    float la = (i == M_) ? LOG_HALF : LOG_NORM;
    float scale = la - (mx + logf(sm));   // u_i
    #pragma unroll
    for (int q = 0; q < 17; ++q) {
        int j = lane + q * 64;
        if (j < NP1) row[j] = expf(t[q] + scale) * 2048.0f;
    }
}

// ---------------- zero helper ----------------
__global__ __launch_bounds__(256) void zero_kernel(float* __restrict__ p, int n)
{
    int i = blockIdx.x * 256 + threadIdx.x;
    if (i < n) p[i] = 0.f;
}

extern "C" void kernel_launch(void* const* d_in, const int* in_sizes, int n_in,
                              void* d_out, int out_size, void* d_ws, size_t ws_size,
                              hipStream_t stream)
{
    const float* tf    = (const float*)d_in[0];
    const float* df    = (const float*)d_in[1];
    const float* tl    = (const float*)d_in[2];
    const float* dl    = (const float*)d_in[3];
    const float* alpha = (const float*)d_in[4];
    const float* eps   = (const float*)d_in[5];
    float* S  = (float*)d_out;
    float* ws = (float*)d_ws;

    float* inv1 = ws;                       // B*1024
    float* inv2 = inv1 + B_ * M_;           // B*1024
    float* u    = inv2 + B_ * N_;           // B*1025
    float* v    = u + B_ * MP1;             // B*1025
    float* pm   = v + B_ * NP1;             // 9*B*1025
    float* ps   = pm + 9 * B_ * NP1;        // 9*B*1025

    // v must be zero at the start of every call (ws is not re-poisoned)
    zero_kernel<<<(B_ * NP1 + 255) / 256, 256, 0, stream>>>(v, B_ * NP1);
    norms_kernel<<<(B_ * 2048) / 4, 256, 0, stream>>>(tf, df, inv1, inv2);
    gemm_s_kernel<<<dim3(8, 8, 16), 256, 0, stream>>>(tf, df, tl, dl, inv1, inv2, eps, S);
    fill_edges_kernel<<<(B_ * (NP1 + M_) + 255) / 256, 256, 0, stream>>>(S, alpha, eps);

    int rowblocks = (B_ * MP1 + 3) / 4;   // 4 waves (rows) per 256-thread block
    for (int it = 0; it < NUM_SINK; ++it) {
        row_pass_kernel<<<rowblocks, 256, 0, stream>>>(S, v, u);
        col_pass1_kernel<<<dim3(5, 9, 16), 256, 0, stream>>>(S, u, pm, ps);
        col_pass2_kernel<<<dim3(5, 16), 256, 0, stream>>>(pm, ps, v);
    }
    row_final_kernel<<<rowblocks, 256, 0, stream>>>(S, v);
}